// Round 1
// baseline (668.617 us; speedup 1.0000x reference)
//
#include <hip/hip_runtime.h>
#include <math.h>

#define NB 16
#define NL 4096
#define NH 8
#define NI 64
#define NO 64
#define NM 64
#define STEP 1.5339807878856412e-3f  // 2*pi/4096

// ---------------------------------------------------------------------------
// K1: forward partial DFT.  sel[b,h,i,m] = sum_l q[b,l,h,i] * e^{-2pi i m l/L}
// Split over LC l-chunks; each block (lc,h,b) writes partial[b][h][lc][m][i][2].
// ---------------------------------------------------------------------------
__global__ __launch_bounds__(256) void k_fwd(const float* __restrict__ q,
                                             float* __restrict__ partial,
                                             int LC, int CHUNK) {
  const int lc = blockIdx.x, h = blockIdx.y, b = blockIdx.z;
  const int t = threadIdx.x;
  __shared__ float2 tw[4096];      // 32 KB twiddle table: tw[t] = (cos, sin)(2pi t/4096)
  __shared__ float qs[64][64];     // 16 KB staged q tile: [l_local][i]

  for (int idx = t; idx < 4096; idx += 256) {
    float s, c;
    sincosf((float)idx * STEP, &s, &c);
    tw[idx] = make_float2(c, s);
  }

  const int i0 = (t & 15) << 2;    // 4 channels per thread
  const int m0 = (t >> 4) << 2;    // 4 modes per thread
  float ar[4][4], ai[4][4];        // [k=m][j=i]
#pragma unroll
  for (int k = 0; k < 4; ++k)
#pragma unroll
    for (int j = 0; j < 4; ++j) { ar[k][j] = 0.f; ai[k][j] = 0.f; }

  const int lstart = lc * CHUNK;
  int pm[4];                       // phase index (m * l) mod 4096, incremented by m each l
#pragma unroll
  for (int k = 0; k < 4; ++k) pm[k] = ((m0 + k) * lstart) & 4095;

  for (int l0 = 0; l0 < CHUNK; l0 += 64) {
    __syncthreads();
    {
      const int r = t >> 2;
      const int c4 = (t & 3) << 4;
      const float4* src = (const float4*)(q + (((size_t)b * NL + (lstart + l0 + r)) * NH + h) * NI + c4);
      float4* dst = (float4*)&qs[r][c4];
      dst[0] = src[0]; dst[1] = src[1]; dst[2] = src[2]; dst[3] = src[3];
    }
    __syncthreads();
#pragma unroll 4
    for (int l = 0; l < 64; ++l) {
      const float4 qv = *(const float4*)&qs[l][i0];
#pragma unroll
      for (int k = 0; k < 4; ++k) {
        const float2 w = tw[pm[k]];
        pm[k] = (pm[k] + m0 + k) & 4095;
        ar[k][0] = fmaf(qv.x, w.x, ar[k][0]);
        ar[k][1] = fmaf(qv.y, w.x, ar[k][1]);
        ar[k][2] = fmaf(qv.z, w.x, ar[k][2]);
        ar[k][3] = fmaf(qv.w, w.x, ar[k][3]);
        ai[k][0] = fmaf(qv.x, w.y, ai[k][0]);
        ai[k][1] = fmaf(qv.y, w.y, ai[k][1]);
        ai[k][2] = fmaf(qv.z, w.y, ai[k][2]);
        ai[k][3] = fmaf(qv.w, w.y, ai[k][3]);
      }
    }
  }
  // partial layout: [b][h][lc][m][i] as float2 (re, im); im = -sum(q*sin)
  float2* dst = (float2*)partial + (((size_t)b * NH + h) * LC + lc) * (NM * NI);
#pragma unroll
  for (int k = 0; k < 4; ++k)
#pragma unroll
    for (int j = 0; j < 4; ++j)
      dst[(m0 + k) * NI + (i0 + j)] = make_float2(ar[k][j], -ai[k][j]);
}

// ---------------------------------------------------------------------------
// K2: reduce partials over lc, then complex mix:
//   out2[b,h,o,m] = sum_i sel[b,h,i,m] * (w1[h,i,o,m] + i w2[h,i,o,m])
// out2 layout: [b][h][m][o] as float2.
// ---------------------------------------------------------------------------
__global__ __launch_bounds__(256) void k_mix(const float* __restrict__ partial,
                                             const float* __restrict__ w1,
                                             const float* __restrict__ w2,
                                             float* __restrict__ out2, int LC) {
  const int og = blockIdx.x, h = blockIdx.y, b = blockIdx.z;
  const int t = threadIdx.x;
  __shared__ float sel_s[2][64][65];   // [re/im][i][m], +1 pad on m

  const float* src = partial + ((size_t)b * NH + h) * LC * (NM * NI * 2);
  for (int u = t; u < NM * NI * 2; u += 256) {
    float v = 0.f;
    for (int lcx = 0; lcx < LC; ++lcx) v += src[(size_t)lcx * (NM * NI * 2) + u];
    sel_s[u & 1][(u >> 1) & 63][u >> 7] = v;
  }
  __syncthreads();

  const int o = og * 16 + (t >> 4);
  const int mt = t & 15;
  float ar[4] = {0.f, 0.f, 0.f, 0.f}, ai[4] = {0.f, 0.f, 0.f, 0.f};
  for (int i = 0; i < NI; ++i) {
    const float* w1p = w1 + (((size_t)h * NI + i) * NO + o) * NM;
    const float* w2p = w2 + (((size_t)h * NI + i) * NO + o) * NM;
#pragma unroll
    for (int k = 0; k < 4; ++k) {
      const int m = mt + (k << 4);
      const float re = sel_s[0][i][m];
      const float im = sel_s[1][i][m];
      const float a = w1p[m];
      const float bb = w2p[m];
      ar[k] = fmaf(re, a, ar[k]);
      ar[k] = fmaf(-im, bb, ar[k]);
      ai[k] = fmaf(re, bb, ai[k]);
      ai[k] = fmaf(im, a, ai[k]);
    }
  }
  float2* dst = (float2*)out2 + ((size_t)b * NH + h) * (NM * NO);
#pragma unroll
  for (int k = 0; k < 4; ++k)
    dst[(mt + (k << 4)) * NO + o] = make_float2(ar[k], ai[k]);
}

// ---------------------------------------------------------------------------
// K3: inverse truncated DFT:
//   x[b,h,o,l] = (1/L) * [ Re0 + 2 * sum_{m=1..63} (Re_m cos - Im_m sin)(2pi m l/L) ]
// Uniform loop m=0..63 with scale fac(m); sin(0)=0 kills Im0 (pocketfft semantics).
// ---------------------------------------------------------------------------
__global__ __launch_bounds__(256) void k_inv(const float* __restrict__ out2,
                                             float* __restrict__ xout) {
  const int lcb = blockIdx.x, h = blockIdx.y, b = blockIdx.z;
  const int t = threadIdx.x;
  __shared__ float2 tw[4096];
  __shared__ float2 oms[NM * NO];      // scaled out2: [m][o]

  for (int idx = t; idx < 4096; idx += 256) {
    float s, c;
    sincosf((float)idx * STEP, &s, &c);
    tw[idx] = make_float2(c, s);
  }
  const float* src = out2 + ((size_t)b * NH + h) * (NM * NO * 2);
  float* omsf = (float*)oms;
  for (int u = t; u < NM * NO * 2; u += 256) {
    const int m = u >> 7;
    const float fac = (m == 0 ? 1.0f : 2.0f) * (1.0f / 4096.0f);
    omsf[u] = src[u] * fac;
  }
  __syncthreads();

  const int o0 = (t & 15) << 2;        // 4 outputs channels per thread
  const int lg = t >> 4;
  const int lbase = lcb * 128 + lg * 8;  // 8 l per thread
  float acc[8][4];
#pragma unroll
  for (int l = 0; l < 8; ++l)
#pragma unroll
    for (int j = 0; j < 4; ++j) acc[l][j] = 0.f;

  for (int mb = 0; mb < NM; mb += 8) {
    float rr[8][4], ri[8][4];
#pragma unroll
    for (int mm = 0; mm < 8; ++mm)
#pragma unroll
      for (int j = 0; j < 4; ++j) {
        const float2 v = oms[(mb + mm) * NO + (o0 + j)];
        rr[mm][j] = v.x; ri[mm][j] = v.y;
      }
#pragma unroll
    for (int l = 0; l < 8; ++l) {
      const int labs = lbase + l;
#pragma unroll
      for (int mm = 0; mm < 8; ++mm) {
        const float2 w = tw[((mb + mm) * labs) & 4095];
#pragma unroll
        for (int j = 0; j < 4; ++j) {
          acc[l][j] = fmaf(rr[mm][j], w.x, acc[l][j]);
          acc[l][j] = fmaf(-ri[mm][j], w.y, acc[l][j]);
        }
      }
    }
  }
#pragma unroll
  for (int j = 0; j < 4; ++j) {
    float* dst = xout + (((size_t)b * NH + h) * NO + (o0 + j)) * NL + lbase;
    float4 v0 = make_float4(acc[0][j], acc[1][j], acc[2][j], acc[3][j]);
    float4 v1 = make_float4(acc[4][j], acc[5][j], acc[6][j], acc[7][j]);
    ((float4*)dst)[0] = v0;
    ((float4*)dst)[1] = v1;
  }
}

extern "C" void kernel_launch(void* const* d_in, const int* in_sizes, int n_in,
                              void* d_out, int out_size, void* d_ws, size_t ws_size,
                              hipStream_t stream) {
  const float* q  = (const float*)d_in[0];
  // d_in[1]=k, d_in[2]=v, d_in[3]=mask are unused by the reference
  const float* w1 = (const float*)d_in[4];
  const float* w2 = (const float*)d_in[5];
  float* out = (float*)d_out;

  const size_t out2Elems = (size_t)NB * NH * NM * NO * 2;  // 1,048,576 floats
  int LC = 1;
  const int cands[3] = {8, 4, 2};
  for (int ci = 0; ci < 3; ++ci) {
    const size_t pe = (size_t)NB * NH * cands[ci] * NM * NI * 2;
    if ((pe + out2Elems) * sizeof(float) <= ws_size) { LC = cands[ci]; break; }
  }
  const size_t partialElems = (size_t)NB * NH * LC * NM * NI * 2;
  float* partial = (float*)d_ws;
  float* out2 = partial + partialElems;

  dim3 blk(256);
  k_fwd<<<dim3(LC, NH, NB), blk, 0, stream>>>(q, partial, LC, NL / LC);
  k_mix<<<dim3(4, NH, NB), blk, 0, stream>>>(partial, w1, w2, out2, LC);
  k_inv<<<dim3(NL / 128, NH, NB), blk, 0, stream>>>(out2, out);
}

// Round 2
// 524.445 us; speedup vs baseline: 1.2749x; 1.2749x over previous
//
#include <hip/hip_runtime.h>
#include <math.h>

#define NB 16
#define NL 4096
#define NH 8
#define NI 64
#define NO 64
#define NM 64
#define QUARTER 1024
#define STEP 1.5339807878856412e-3f  // 2*pi/4096

// skewed slot: breaks power-of-2 stride bank patterns (16 lanes stride 32 -> spread)
__device__ __forceinline__ int sk(int p) { return p + (p >> 5); }

// ---------------------------------------------------------------------------
// K1: forward truncated DFT with one radix-4 decimation over l.
//   l = l' + 1024*p, coef (-i)^(m*p):
//     m%4==0: S = (q0+q2)+(q1+q3)         (real)
//     m%4==2: D = (q0+q2)-(q1+q3)         (real)
//     m%4==1: G - iH,  m%4==3: G + iH,  G=q0-q2, H=q1-q3
//   sel[m] = sum_{l'<1024} inner_m(l') * (cos - i sin)(2pi m l'/4096)
// Grid (LCF, NH, NB); each block handles CHUNK = 1024/LCF l' values, writes
// partial[b][h][lc][m][i] (complex).
// ---------------------------------------------------------------------------
__global__ __launch_bounds__(256) void k_fwd(const float* __restrict__ q,
                                             float* __restrict__ partial,
                                             int LCF, int CHUNK) {
  const int lc = blockIdx.x, h = blockIdx.y, b = blockIdx.z;
  const int t = threadIdx.x;
  __shared__ float ct[4096];        // plain cos table (reads are wave-broadcast)
  __shared__ float4 prep[16][64];   // {S, D, G, H} per [l'_local][i]

  for (int idx = t; idx < 4096; idx += 256) ct[idx] = cosf((float)idx * STEP);

  const int ig = t & 15;            // i-group; thread's i = ig + 16*j
  const int m0 = (t >> 4) << 2;     // 4 consecutive m -> residues 0,1,2,3
  float ar[4][4], ai[4][4];         // [k=residue][j=i]
#pragma unroll
  for (int k = 0; k < 4; ++k)
#pragma unroll
    for (int j = 0; j < 4; ++j) { ar[k][j] = 0.f; ai[k][j] = 0.f; }

  const int lstart = lc * CHUNK;

  for (int tt = 0; tt < CHUNK; tt += 16) {
    __syncthreads();  // previous tile's readers done before overwrite
    {
      const int iA = t & 63;
#pragma unroll
      for (int c = 0; c < 4; ++c) {
        const int lloc = (t >> 6) + (c << 2);
        const int labs = lstart + tt + lloc;        // l' in [0,1024)
        const float* qp = q + (((size_t)b * NL + labs) * NH + h) * NI + iA;
        const float q0 = qp[0];
        const float q1 = qp[(size_t)QUARTER * NH * NI];
        const float q2 = qp[(size_t)2 * QUARTER * NH * NI];
        const float q3 = qp[(size_t)3 * QUARTER * NH * NI];
        const float E = q0 + q2, F = q1 + q3;
        prep[lloc][iA] = make_float4(E + F, E - F, q0 - q2, q1 - q3);
      }
    }
    __syncthreads();
#pragma unroll 2
    for (int ll = 0; ll < 16; ++ll) {
      const int la = lstart + tt + ll;
      const int p0 = (m0 * la) & 4095;
      const int p1 = (p0 + la) & 4095;
      const int p2 = (p1 + la) & 4095;
      const int p3 = (p2 + la) & 4095;
      const float c0 = ct[p0], s0 = ct[(p0 + 3072) & 4095];
      const float c1 = ct[p1], s1 = ct[(p1 + 3072) & 4095];
      const float c2 = ct[p2], s2 = ct[(p2 + 3072) & 4095];
      const float c3 = ct[p3], s3 = ct[(p3 + 3072) & 4095];
#pragma unroll
      for (int j = 0; j < 4; ++j) {
        const float4 f = prep[ll][ig + (j << 4)];
        // m0+0: real S = f.x
        ar[0][j] = fmaf(f.x, c0, ar[0][j]);
        ai[0][j] = fmaf(-f.x, s0, ai[0][j]);
        // m0+1: (G - iH)(c - i s) -> re += Gc - Hs; im -= Gs + Hc
        ar[1][j] = fmaf(f.z, c1, ar[1][j]);
        ar[1][j] = fmaf(-f.w, s1, ar[1][j]);
        ai[1][j] = fmaf(-f.z, s1, ai[1][j]);
        ai[1][j] = fmaf(-f.w, c1, ai[1][j]);
        // m0+2: real D = f.y
        ar[2][j] = fmaf(f.y, c2, ar[2][j]);
        ai[2][j] = fmaf(-f.y, s2, ai[2][j]);
        // m0+3: (G + iH)(c - i s) -> re += Gc + Hs; im += Hc - Gs
        ar[3][j] = fmaf(f.z, c3, ar[3][j]);
        ar[3][j] = fmaf(f.w, s3, ar[3][j]);
        ai[3][j] = fmaf(f.w, c3, ai[3][j]);
        ai[3][j] = fmaf(-f.z, s3, ai[3][j]);
      }
    }
  }
  float2* dst = (float2*)partial + (((size_t)b * NH + h) * LCF + lc) * (NM * NI);
#pragma unroll
  for (int k = 0; k < 4; ++k)
#pragma unroll
    for (int j = 0; j < 4; ++j)
      dst[(m0 + k) * NI + (ig + (j << 4))] = make_float2(ar[k][j], ai[k][j]);
}

// ---------------------------------------------------------------------------
// K2: reduce partials over lc, then complex mix:
//   out2[b,h,m,o] = sum_i sel[b,h,i,m] * (w1[h,i,o,m] + i w2[h,i,o,m])
// ---------------------------------------------------------------------------
__global__ __launch_bounds__(256) void k_mix(const float* __restrict__ partial,
                                             const float* __restrict__ w1,
                                             const float* __restrict__ w2,
                                             float* __restrict__ out2, int LCF) {
  const int og = blockIdx.x, h = blockIdx.y, b = blockIdx.z;
  const int t = threadIdx.x;
  __shared__ float sel_s[2][64][65];   // [re/im][i][m], +1 pad on m

  const float* src = partial + ((size_t)b * NH + h) * LCF * (NM * NI * 2);
  for (int u = t; u < NM * NI * 2; u += 256) {
    float v = 0.f;
    for (int lcx = 0; lcx < LCF; ++lcx) v += src[(size_t)lcx * (NM * NI * 2) + u];
    sel_s[u & 1][(u >> 1) & 63][u >> 7] = v;
  }
  __syncthreads();

  const int o = og * 16 + (t >> 4);
  const int mt = t & 15;
  float ar[4] = {0.f, 0.f, 0.f, 0.f}, ai[4] = {0.f, 0.f, 0.f, 0.f};
  for (int i = 0; i < NI; ++i) {
    const float* w1p = w1 + (((size_t)h * NI + i) * NO + o) * NM;
    const float* w2p = w2 + (((size_t)h * NI + i) * NO + o) * NM;
#pragma unroll
    for (int k = 0; k < 4; ++k) {
      const int m = mt + (k << 4);
      const float re = sel_s[0][i][m];
      const float im = sel_s[1][i][m];
      const float a = w1p[m];
      const float bb = w2p[m];
      ar[k] = fmaf(re, a, ar[k]);
      ar[k] = fmaf(-im, bb, ar[k]);
      ai[k] = fmaf(re, bb, ai[k]);
      ai[k] = fmaf(im, a, ai[k]);
    }
  }
  float2* dst = (float2*)out2 + ((size_t)b * NH + h) * (NM * NO);
#pragma unroll
  for (int k = 0; k < 4; ++k)
    dst[(mt + (k << 4)) * NO + o] = make_float2(ar[k], ai[k]);
}

// ---------------------------------------------------------------------------
// K3: inverse truncated DFT, radix-4 DIT.
//   out[o, l' + 1024p] = Re( sum_r i^{rp} T_r ),  T_r = sum_{m=r mod 4} c_m e^{i 2pi m l'/4096}
//   c_m = fac(m) * (Re' + i Im'),  fac = (m==0?1:2)/4096
// Thread: 4 o x 2 l'; block: 64 o x 32 l'; grid (32, NH, NB).
// ---------------------------------------------------------------------------
__global__ __launch_bounds__(256) void k_inv(const float* __restrict__ out2,
                                             float* __restrict__ xout) {
  const int lb = blockIdx.x, h = blockIdx.y, b = blockIdx.z;
  const int t = threadIdx.x;
  __shared__ float ct[4224];           // skewed cos table
  __shared__ float2 oms[NM * NO];      // scaled coeffs [m][o]

  for (int idx = t; idx < 4096; idx += 256) ct[sk(idx)] = cosf((float)idx * STEP);

  const float* src = out2 + ((size_t)b * NH + h) * (NM * NO * 2);
  float* omsf = (float*)oms;
  for (int u = t; u < NM * NO * 2; u += 256) {
    const int m = u >> 7;
    const float fac = (m == 0 ? 1.0f : 2.0f) * (1.0f / 4096.0f);
    omsf[u] = src[u] * fac;
  }
  __syncthreads();

  const int lg = t & 15;
  const int og = t >> 4;
  const int o0 = og << 2;
  const int l0 = (lb << 5) + (lg << 1);   // thread's l' pair: l0, l0+1

  float Tr[4][2][4], Ti[4][2][4];      // [r][ll][o]
#pragma unroll
  for (int r = 0; r < 4; ++r)
#pragma unroll
    for (int ll = 0; ll < 2; ++ll)
#pragma unroll
      for (int j = 0; j < 4; ++j) { Tr[r][ll][j] = 0.f; Ti[r][ll][j] = 0.f; }

#pragma unroll
  for (int r = 0; r < 4; ++r) {
    int p0 = (r * l0) & 4095;
    int p1 = (r * (l0 + 1)) & 4095;
    const int d0 = (l0 << 2) & 4095;
    const int d1 = ((l0 + 1) << 2) & 4095;
#pragma unroll 2
    for (int m = r; m < NM; m += 4) {
      const float4 ca = ((const float4*)&oms[m * NO + o0])[0];
      const float4 cb = ((const float4*)&oms[m * NO + o0])[1];
      const float cre[4] = {ca.x, ca.z, cb.x, cb.z};
      const float cim[4] = {ca.y, ca.w, cb.y, cb.w};
      const float c_0 = ct[sk(p0)], s_0 = ct[sk((p0 + 3072) & 4095)];
      const float c_1 = ct[sk(p1)], s_1 = ct[sk((p1 + 3072) & 4095)];
      p0 = (p0 + d0) & 4095;
      p1 = (p1 + d1) & 4095;
#pragma unroll
      for (int j = 0; j < 4; ++j) {
        Tr[r][0][j] = fmaf(cre[j], c_0, Tr[r][0][j]);
        Tr[r][0][j] = fmaf(-cim[j], s_0, Tr[r][0][j]);
        Ti[r][0][j] = fmaf(cre[j], s_0, Ti[r][0][j]);
        Ti[r][0][j] = fmaf(cim[j], c_0, Ti[r][0][j]);
        Tr[r][1][j] = fmaf(cre[j], c_1, Tr[r][1][j]);
        Tr[r][1][j] = fmaf(-cim[j], s_1, Tr[r][1][j]);
        Ti[r][1][j] = fmaf(cre[j], s_1, Ti[r][1][j]);
        Ti[r][1][j] = fmaf(cim[j], c_1, Ti[r][1][j]);
      }
    }
  }

  const size_t obase = ((size_t)b * NH + h) * NO * (size_t)NL;
#pragma unroll
  for (int j = 0; j < 4; ++j) {
    float* orow = xout + obase + (size_t)(o0 + j) * NL;
    float v[4][2];
#pragma unroll
    for (int ll = 0; ll < 2; ++ll) {
      const float a  = Tr[0][ll][j] + Tr[2][ll][j];
      const float bb = Tr[1][ll][j] + Tr[3][ll][j];
      const float c  = Tr[0][ll][j] - Tr[2][ll][j];
      const float d  = Ti[1][ll][j] - Ti[3][ll][j];
      v[0][ll] = a + bb;   // p=0
      v[1][ll] = c - d;    // p=1
      v[2][ll] = a - bb;   // p=2
      v[3][ll] = c + d;    // p=3
    }
#pragma unroll
    for (int p = 0; p < 4; ++p)
      *(float2*)(orow + p * QUARTER + l0) = make_float2(v[p][0], v[p][1]);
  }
}

extern "C" void kernel_launch(void* const* d_in, const int* in_sizes, int n_in,
                              void* d_out, int out_size, void* d_ws, size_t ws_size,
                              hipStream_t stream) {
  const float* q  = (const float*)d_in[0];
  // d_in[1]=k, d_in[2]=v, d_in[3]=mask unused by the reference
  const float* w1 = (const float*)d_in[4];
  const float* w2 = (const float*)d_in[5];
  float* out = (float*)d_out;

  const size_t out2Elems = (size_t)NB * NH * NM * NO * 2;  // 1,048,576 floats
  int LCF = 1;
  const int cands[4] = {8, 4, 2, 1};
  for (int ci = 0; ci < 4; ++ci) {
    const size_t pe = (size_t)NB * NH * cands[ci] * NM * NI * 2;
    if ((pe + out2Elems) * sizeof(float) <= ws_size) { LCF = cands[ci]; break; }
  }
  const size_t partialElems = (size_t)NB * NH * LCF * NM * NI * 2;
  float* partial = (float*)d_ws;
  float* out2 = partial + partialElems;

  dim3 blk(256);
  k_fwd<<<dim3(LCF, NH, NB), blk, 0, stream>>>(q, partial, LCF, QUARTER / LCF);
  k_mix<<<dim3(4, NH, NB), blk, 0, stream>>>(partial, w1, w2, out2, LCF);
  k_inv<<<dim3(32, NH, NB), blk, 0, stream>>>(out2, out);
}